// Round 7
// baseline (4081.411 us; speedup 1.0000x reference)
//
#include <hip/hip_runtime.h>

#define NQ   32768
#define NE   8192
#define DIM  256
#define HWsz 1024
#define MARGIN 4e-4f
#define CAP  128

typedef __attribute__((ext_vector_type(8))) short short8;
typedef __attribute__((ext_vector_type(4))) float f32x4;

#define GLDS16(gp, lp) __builtin_amdgcn_global_load_lds( \
    (const __attribute__((address_space(1))) unsigned int*)(gp), \
    (__attribute__((address_space(3))) unsigned int*)(lp), 16, 0, 0)

static __device__ inline unsigned short f2bf(float f) {
  unsigned int u = __float_as_uint(f);
  unsigned int r = (u + 0x7fff + ((u >> 16) & 1)) >> 16;
  return (unsigned short)r;
}

// ---------- se[c] = sum(emb[c,:]^2) ----------
__global__ __launch_bounds__(256) void k_se(const float* __restrict__ emb,
                                            float* __restrict__ se) {
  int w = threadIdx.x >> 6;
  int l = threadIdx.x & 63;
  int r = blockIdx.x * 4 + w;
  float4 v = *(const float4*)(emb + (size_t)r * DIM + l * 4);
  float s = (v.x * v.x + v.y * v.y) + (v.z * v.z + v.w * v.w);
  #pragma unroll
  for (int m = 32; m >= 1; m >>= 1) s += __shfl_xor(s, m);
  if (l == 0) se[r] = s;
}

// ---------- s2[n] = sum over channels of z^2 ----------
__global__ __launch_bounds__(256) void k_s2(const float* __restrict__ z,
                                            float* __restrict__ s2) {
  __shared__ float red[4][64];
  int blk = blockIdx.x;
  int b = blk >> 4;
  int hw0 = (blk & 15) << 6;
  int q = threadIdx.x & 63;
  int p = threadIdx.x >> 6;
  const float* zp = z + (size_t)(b * DIM + p * 64) * HWsz + hw0 + q;
  float s = 0.f;
  #pragma unroll 4
  for (int c = 0; c < 64; ++c) {
    float v = zp[(size_t)c * HWsz];
    s = fmaf(v, v, s);
  }
  red[p][q] = s;
  __syncthreads();
  if (threadIdx.x < 64) {
    s2[blk * 64 + q] = (red[0][q] + red[1][q]) + (red[2][q] + red[3][q]);
  }
}

// ---------- emb fp32 [c][k] -> bf16 tile-image ebf (layout as rounds 2-6) ----------
__global__ __launch_bounds__(256) void k_ebf(const float* __restrict__ emb,
                                             unsigned short* __restrict__ ebf) {
  int gid = blockIdx.x * 256 + threadIdx.x;
  int t32 = gid >> 10;
  int wi = gid & 1023;
  int cf = wi >> 9;
  int kk = (wi >> 6) & 7;
  int l = wi & 63;
  int row = t32 * 32 + cf * 16 + (l & 15);
  int col = (l >> 4) * 8 + kk * 32;
  const float* src = emb + (size_t)row * DIM + col;
  float4 v0 = *(const float4*)(src);
  float4 v1 = *(const float4*)(src + 4);
  unsigned short o[8] = {f2bf(v0.x), f2bf(v0.y), f2bf(v0.z), f2bf(v0.w),
                         f2bf(v1.x), f2bf(v1.y), f2bf(v1.z), f2bf(v1.w)};
  *(short8*)(ebf + (size_t)gid * 8) = *(short8*)o;
}

// ---------- z [b][ch][hw] fp32 -> za [q][ch] bf16 (tiled LDS transpose) ----------
__global__ __launch_bounds__(256) void k_tr(const float* __restrict__ z,
                                            unsigned short* __restrict__ za) {
  __shared__ float lt[64][65];
  int blk = blockIdx.x;
  int b = blk >> 6;
  int r = blk & 63;
  int ch0 = (r >> 4) * 64;
  int hw0 = (r & 15) * 64;
  int tid = threadIdx.x;
  #pragma unroll
  for (int p = 0; p < 4; ++p) {
    int idx = p * 256 + tid;
    int ch = idx >> 4;
    int hc = idx & 15;
    float4 v = *(const float4*)(z + (size_t)(b * DIM + ch0 + ch) * HWsz + hw0 + hc * 4);
    lt[ch][hc * 4 + 0] = v.x;
    lt[ch][hc * 4 + 1] = v.y;
    lt[ch][hc * 4 + 2] = v.z;
    lt[ch][hc * 4 + 3] = v.w;
  }
  __syncthreads();
  #pragma unroll
  for (int p = 0; p < 2; ++p) {
    int idx = p * 256 + tid;
    int hw = idx >> 3;
    int cc = idx & 7;
    unsigned short o[8];
    #pragma unroll
    for (int j = 0; j < 8; ++j) o[j] = f2bf(lt[cc * 8 + j][hw]);
    *(short8*)(za + (size_t)((b << 10) + hw0 + hw) * DIM + ch0 + cc * 8) = *(short8*)o;
  }
}

// ---------- fused single MFMA sweep: running-threshold candidate collection ----------
// grid 2048: qb = blk>>3 (128 queries), ct = blk&7 (1024 codes = 32 periods of 32)
// wave owns 32 queries (f=2); swapped operands: D[c][q], q=lane&15
__global__ __launch_bounds__(256, 4) void k_score(const unsigned short* __restrict__ za,
                                                  const unsigned short* __restrict__ ebf,
                                                  int* __restrict__ cnt,
                                                  unsigned int* __restrict__ cand,
                                                  float* __restrict__ qbest) {
  __shared__ __align__(16) char ebt[2][16384];
  const int tid = threadIdx.x, lane = tid & 63, w = tid >> 6;
  const int qb = blockIdx.x >> 3, ct = blockIdx.x & 7;
  const int q0w = qb * 128 + w * 32;
  const char* ebase = (const char*)ebf + (size_t)ct * 32 * 16384;

  short8 a[2][8];
  #pragma unroll
  for (int f = 0; f < 2; ++f)
    #pragma unroll
    for (int kk = 0; kk < 8; ++kk)
      a[f][kk] = *(const short8*)(za + (size_t)(q0w + f * 16 + (lane & 15)) * DIM
                                  + (lane >> 4) * 8 + kk * 32);

  float runmax[2] = {-3.4028235e38f, -3.4028235e38f};

  #pragma unroll
  for (int j = 0; j < 4; ++j)
    GLDS16(ebase + (j * 256 + tid) * 16, &ebt[0][(j * 256 + tid) * 16]);
  asm volatile("s_waitcnt vmcnt(0)" ::: "memory");
  __builtin_amdgcn_s_barrier();

  int cur = 0;
  for (int t = 0; t < 32; ++t) {
    if (t < 31) {
      const char* src = ebase + (size_t)(t + 1) * 16384;
      #pragma unroll
      for (int j = 0; j < 4; ++j)
        GLDS16(src + (j * 256 + tid) * 16, &ebt[cur ^ 1][(j * 256 + tid) * 16]);
    }
    __builtin_amdgcn_sched_barrier(0);

    f32x4 acc[2][2];
    #pragma unroll
    for (int f = 0; f < 2; ++f) {
      acc[f][0] = (f32x4){0.f, 0.f, 0.f, 0.f};
      acc[f][1] = (f32x4){0.f, 0.f, 0.f, 0.f};
    }
    #pragma unroll
    for (int kk = 0; kk < 8; ++kk) {
      short8 b0 = *(const short8*)&ebt[cur][kk * 1024 + lane * 16];
      short8 b1 = *(const short8*)&ebt[cur][8192 + kk * 1024 + lane * 16];
      #pragma unroll
      for (int f = 0; f < 2; ++f) {
        acc[f][0] = __builtin_amdgcn_mfma_f32_16x16x32_bf16(b0, a[f][kk], acc[f][0], 0, 0, 0);
        acc[f][1] = __builtin_amdgcn_mfma_f32_16x16x32_bf16(b1, a[f][kk], acc[f][1], 0, 0, 0);
      }
    }
    int cbase0 = ct * 1024 + t * 32 + (lane >> 4) * 4;
    #pragma unroll
    for (int f = 0; f < 2; ++f) {
      float vmax = fmaxf(fmaxf(fmaxf(acc[f][0][0], acc[f][0][1]), fmaxf(acc[f][0][2], acc[f][0][3])),
                         fmaxf(fmaxf(acc[f][1][0], acc[f][1][1]), fmaxf(acc[f][1][2], acc[f][1][3])));
      float v = fmaxf(vmax, __shfl_xor(vmax, 16));
      v = fmaxf(v, __shfl_xor(v, 32));
      runmax[f] = fmaxf(runmax[f], v);
      float thr = runmax[f] - MARGIN;
      if (vmax >= thr) {
        unsigned int hm = 0;
        hm |= (acc[f][0][0] >= thr) ? 0x01u : 0u;
        hm |= (acc[f][0][1] >= thr) ? 0x02u : 0u;
        hm |= (acc[f][0][2] >= thr) ? 0x04u : 0u;
        hm |= (acc[f][0][3] >= thr) ? 0x08u : 0u;
        hm |= (acc[f][1][0] >= thr) ? 0x10u : 0u;
        hm |= (acc[f][1][1] >= thr) ? 0x20u : 0u;
        hm |= (acc[f][1][2] >= thr) ? 0x40u : 0u;
        hm |= (acc[f][1][3] >= thr) ? 0x80u : 0u;
        int q = q0w + f * 16 + (lane & 15);
        int pos = atomicAdd(&cnt[q], __popc(hm));
        #pragma unroll
        for (int j = 0; j < 2; ++j)
          #pragma unroll
          for (int r = 0; r < 4; ++r)
            if (hm & (1u << (j * 4 + r))) {
              if (pos < CAP)
                cand[((size_t)q << 7) + pos] =
                    (__float_as_uint(acc[f][j][r]) & 0xFFFFE000u) |
                    (unsigned int)(cbase0 + j * 16 + r);
              ++pos;
            }
      }
    }
    asm volatile("s_waitcnt vmcnt(0)" ::: "memory");
    __builtin_amdgcn_s_barrier();
    cur ^= 1;
  }
  // store exact per-split final max (for exact global threshold in rescore)
  #pragma unroll
  for (int f = 0; f < 2; ++f)
    if (lane < 16) qbest[(size_t)ct * NQ + q0w + f * 16 + lane] = runmax[f];
}

// ---------- exact fp32 rescore: exact global thr, filter stored, rescore ----------
__global__ __launch_bounds__(256) void k_rescore(const float* __restrict__ z,
                                                 const float* __restrict__ emb,
                                                 const float* __restrict__ se,
                                                 const float* __restrict__ s2,
                                                 const int* __restrict__ cnt,
                                                 const unsigned int* __restrict__ cand,
                                                 const float* __restrict__ qbest,
                                                 int* __restrict__ best) {
  int q = blockIdx.x * 4 + (threadIdx.x >> 6);
  int lane = threadIdx.x & 63;
  int b = q >> 10;
  int hw = q & 1023;
  float zr[4];
  #pragma unroll
  for (int j = 0; j < 4; ++j)
    zr[j] = z[(size_t)((b << 8) + lane * 4 + j) * HWsz + hw];
  float s2q = s2[q];
  int n = cnt[q];
  float bd = 3.4028235e38f;
  int bi = 0x7fffffff;
  if (n > 0 && n <= CAP) {
    float M = -3.4028235e38f;
    #pragma unroll
    for (int ct = 0; ct < 8; ++ct) M = fmaxf(M, qbest[(size_t)ct * NQ + q]);
    float thr = M - MARGIN - 4e-6f;   // packing-truncation guard
    unsigned int p0 = (lane < n) ? cand[((size_t)q << 7) + lane] : 0u;
    unsigned int p1 = (lane + 64 < n) ? cand[((size_t)q << 7) + lane + 64] : 0u;
    bool h0 = (lane < n) && (__uint_as_float(p0 & 0xFFFFE000u) >= thr);
    bool h1 = (lane + 64 < n) && (__uint_as_float(p1 & 0xFFFFE000u) >= thr);
    #pragma unroll
    for (int half = 0; half < 2; ++half) {
      unsigned long long mask = __ballot(half == 0 ? h0 : h1);
      unsigned int pw = half == 0 ? p0 : p1;
      while (mask) {
        int sl = __ffsll(mask) - 1;
        mask &= mask - 1;
        int c = __shfl((int)pw, sl) & 0x1FFF;
        float4 e = *(const float4*)(emb + (size_t)c * DIM + lane * 4);
        float pr = fmaf(zr[0], e.x, fmaf(zr[1], e.y, fmaf(zr[2], e.z, zr[3] * e.w)));
        #pragma unroll
        for (int m = 1; m <= 32; m <<= 1) pr += __shfl_xor(pr, m);
        float tt = s2q + se[c];
        float d = tt - 2.0f * pr;
        if (d < bd || (d == bd && c < bi)) { bd = d; bi = c; }
      }
    }
  } else {
    for (int c = 0; c < NE; ++c) {
      float4 e = *(const float4*)(emb + (size_t)c * DIM + lane * 4);
      float pr = fmaf(zr[0], e.x, fmaf(zr[1], e.y, fmaf(zr[2], e.z, zr[3] * e.w)));
      #pragma unroll
      for (int m = 1; m <= 32; m <<= 1) pr += __shfl_xor(pr, m);
      float tt = s2q + se[c];
      float d = tt - 2.0f * pr;
      if (d < bd || (d == bd && c < bi)) { bd = d; bi = c; }
    }
  }
  if (lane == 0) best[q] = bi;
}

// ---------- output writer: z_q (straight-through) + indices as float ----------
__global__ __launch_bounds__(256) void k_out(const float* __restrict__ z,
                                             const float* __restrict__ emb,
                                             const int* __restrict__ best,
                                             float* __restrict__ out) {
  int i = blockIdx.x * 256 + threadIdx.x;
  if (i < NQ * DIM) {
    int bb = i >> 18;
    int c  = (i >> 10) & 255;
    int hw = i & 1023;
    int n  = (bb << 10) + hw;
    float zv = z[i];
    float evv = emb[(size_t)best[n] * DIM + c];
    out[i] = zv + (evv - zv);
  } else {
    int n = i - NQ * DIM;
    out[i] = (float)best[n];
  }
}

extern "C" void kernel_launch(void* const* d_in, const int* in_sizes, int n_in,
                              void* d_out, int out_size, void* d_ws, size_t ws_size,
                              hipStream_t stream) {
  const float* z   = (const float*)d_in[0];
  const float* emb = (const float*)d_in[1];
  float* out = (float*)d_out;

  char* ws = (char*)d_ws;
  float*        se    = (float*)(ws + 0);                   //  32 KB
  float*        s2    = (float*)(ws + 32768);               // 128 KB
  int*          best  = (int*)  (ws + 163840);              // 128 KB
  int*          cnt   = (int*)  (ws + 294912);              // 128 KB
  float*        qbest = (float*)(ws + 425984);              //   1 MB (8 x NQ f32)
  unsigned int* cand  = (unsigned int*)(ws + 1474560);      //  16 MB (NQ x 128 u32)
  unsigned short* za  = (unsigned short*)(ws + 18251776);   //  16 MB
  unsigned short* ebf = (unsigned short*)(ws + 35028992);   //   4 MB  (total ~37.5 MB)

  k_se     <<<NE / 4, 256, 0, stream>>>(emb, se);
  k_s2     <<<NQ / 64, 256, 0, stream>>>(z, s2);
  k_ebf    <<<1024, 256, 0, stream>>>(emb, ebf);
  k_tr     <<<2048, 256, 0, stream>>>(z, za);
  hipMemsetAsync(cnt, 0, NQ * sizeof(int), stream);
  k_score  <<<2048, 256, 0, stream>>>(za, ebf, cnt, cand, qbest);
  k_rescore<<<NQ / 4, 256, 0, stream>>>(z, emb, se, s2, cnt, cand, qbest, best);
  k_out    <<<(NQ * DIM + NQ) / 256, 256, 0, stream>>>(z, emb, best, out);
}

// Round 8
// 356.421 us; speedup vs baseline: 11.4511x; 11.4511x over previous
//
#include <hip/hip_runtime.h>

#define NQ   32768
#define NE   8192
#define DIM  256
#define HWsz 1024
#define MARGIN 4e-4f
#define CAP  128

typedef __attribute__((ext_vector_type(8))) short short8;
typedef __attribute__((ext_vector_type(4))) float f32x4;

#define GLDS16(gp, lp) __builtin_amdgcn_global_load_lds( \
    (const __attribute__((address_space(1))) unsigned int*)(gp), \
    (__attribute__((address_space(3))) unsigned int*)(lp), 16, 0, 0)

static __device__ inline unsigned short f2bf(float f) {
  unsigned int u = __float_as_uint(f);
  unsigned int r = (u + 0x7fff + ((u >> 16) & 1)) >> 16;
  return (unsigned short)r;
}

// ---------- se[c] = sum(emb[c,:]^2) ----------
__global__ __launch_bounds__(256) void k_se(const float* __restrict__ emb,
                                            float* __restrict__ se) {
  int w = threadIdx.x >> 6;
  int l = threadIdx.x & 63;
  int r = blockIdx.x * 4 + w;
  float4 v = *(const float4*)(emb + (size_t)r * DIM + l * 4);
  float s = (v.x * v.x + v.y * v.y) + (v.z * v.z + v.w * v.w);
  #pragma unroll
  for (int m = 32; m >= 1; m >>= 1) s += __shfl_xor(s, m);
  if (l == 0) se[r] = s;
}

// ---------- s2[n] = sum over channels of z^2 ----------
__global__ __launch_bounds__(256) void k_s2(const float* __restrict__ z,
                                            float* __restrict__ s2) {
  __shared__ float red[4][64];
  int blk = blockIdx.x;
  int b = blk >> 4;
  int hw0 = (blk & 15) << 6;
  int q = threadIdx.x & 63;
  int p = threadIdx.x >> 6;
  const float* zp = z + (size_t)(b * DIM + p * 64) * HWsz + hw0 + q;
  float s = 0.f;
  #pragma unroll 4
  for (int c = 0; c < 64; ++c) {
    float v = zp[(size_t)c * HWsz];
    s = fmaf(v, v, s);
  }
  red[p][q] = s;
  __syncthreads();
  if (threadIdx.x < 64) {
    s2[blk * 64 + q] = (red[0][q] + red[1][q]) + (red[2][q] + red[3][q]);
  }
}

// ---------- emb fp32 [c][k] -> bf16 tile-image ebf (layout as rounds 2-7) ----------
__global__ __launch_bounds__(256) void k_ebf(const float* __restrict__ emb,
                                             unsigned short* __restrict__ ebf) {
  int gid = blockIdx.x * 256 + threadIdx.x;
  int t32 = gid >> 10;
  int wi = gid & 1023;
  int cf = wi >> 9;
  int kk = (wi >> 6) & 7;
  int l = wi & 63;
  int row = t32 * 32 + cf * 16 + (l & 15);
  int col = (l >> 4) * 8 + kk * 32;
  const float* src = emb + (size_t)row * DIM + col;
  float4 v0 = *(const float4*)(src);
  float4 v1 = *(const float4*)(src + 4);
  unsigned short o[8] = {f2bf(v0.x), f2bf(v0.y), f2bf(v0.z), f2bf(v0.w),
                         f2bf(v1.x), f2bf(v1.y), f2bf(v1.z), f2bf(v1.w)};
  *(short8*)(ebf + (size_t)gid * 8) = *(short8*)o;
}

// ---------- z [b][ch][hw] fp32 -> za [q][ch] bf16 (tiled LDS transpose) ----------
__global__ __launch_bounds__(256) void k_tr(const float* __restrict__ z,
                                            unsigned short* __restrict__ za) {
  __shared__ float lt[64][65];
  int blk = blockIdx.x;
  int b = blk >> 6;
  int r = blk & 63;
  int ch0 = (r >> 4) * 64;
  int hw0 = (r & 15) * 64;
  int tid = threadIdx.x;
  #pragma unroll
  for (int p = 0; p < 4; ++p) {
    int idx = p * 256 + tid;
    int ch = idx >> 4;
    int hc = idx & 15;
    float4 v = *(const float4*)(z + (size_t)(b * DIM + ch0 + ch) * HWsz + hw0 + hc * 4);
    lt[ch][hc * 4 + 0] = v.x;
    lt[ch][hc * 4 + 1] = v.y;
    lt[ch][hc * 4 + 2] = v.z;
    lt[ch][hc * 4 + 3] = v.w;
  }
  __syncthreads();
  #pragma unroll
  for (int p = 0; p < 2; ++p) {
    int idx = p * 256 + tid;
    int hw = idx >> 3;
    int cc = idx & 7;
    unsigned short o[8];
    #pragma unroll
    for (int j = 0; j < 8; ++j) o[j] = f2bf(lt[cc * 8 + j][hw]);
    *(short8*)(za + (size_t)((b << 10) + hw0 + hw) * DIM + ch0 + cc * 8) = *(short8*)o;
  }
}

// ---------- fused single MFMA sweep: running-threshold candidate collection ----------
// grid 1024: qb = blk>>2 (128 queries), ct = blk&3 (2048 codes = 64 periods of 32)
// wave owns 32 queries (f=2); swapped operands: D[c][q], q=lane&15
// 4-split collection stats validated in round 6 (CAP=128, zero overflow)
__global__ __launch_bounds__(256, 4) void k_score(const unsigned short* __restrict__ za,
                                                  const unsigned short* __restrict__ ebf,
                                                  int* __restrict__ cnt,
                                                  unsigned int* __restrict__ cand,
                                                  float* __restrict__ qbest) {
  __shared__ __align__(16) char ebt[2][16384];
  const int tid = threadIdx.x, lane = tid & 63, w = tid >> 6;
  const int qb = blockIdx.x >> 2, ct = blockIdx.x & 3;
  const int q0w = qb * 128 + w * 32;
  const char* ebase = (const char*)ebf + (size_t)ct * 64 * 16384;

  short8 a[2][8];
  #pragma unroll
  for (int f = 0; f < 2; ++f)
    #pragma unroll
    for (int kk = 0; kk < 8; ++kk)
      a[f][kk] = *(const short8*)(za + (size_t)(q0w + f * 16 + (lane & 15)) * DIM
                                  + (lane >> 4) * 8 + kk * 32);

  float runmax[2] = {-3.4028235e38f, -3.4028235e38f};

  #pragma unroll
  for (int j = 0; j < 4; ++j)
    GLDS16(ebase + (j * 256 + tid) * 16, &ebt[0][(j * 256 + tid) * 16]);
  asm volatile("s_waitcnt vmcnt(0)" ::: "memory");
  __builtin_amdgcn_s_barrier();

  int cur = 0;
  for (int t = 0; t < 64; ++t) {
    if (t < 63) {
      const char* src = ebase + (size_t)(t + 1) * 16384;
      #pragma unroll
      for (int j = 0; j < 4; ++j)
        GLDS16(src + (j * 256 + tid) * 16, &ebt[cur ^ 1][(j * 256 + tid) * 16]);
    }
    __builtin_amdgcn_sched_barrier(0);

    f32x4 acc[2][2];
    #pragma unroll
    for (int f = 0; f < 2; ++f) {
      acc[f][0] = (f32x4){0.f, 0.f, 0.f, 0.f};
      acc[f][1] = (f32x4){0.f, 0.f, 0.f, 0.f};
    }
    #pragma unroll
    for (int kk = 0; kk < 8; ++kk) {
      short8 b0 = *(const short8*)&ebt[cur][kk * 1024 + lane * 16];
      short8 b1 = *(const short8*)&ebt[cur][8192 + kk * 1024 + lane * 16];
      #pragma unroll
      for (int f = 0; f < 2; ++f) {
        acc[f][0] = __builtin_amdgcn_mfma_f32_16x16x32_bf16(b0, a[f][kk], acc[f][0], 0, 0, 0);
        acc[f][1] = __builtin_amdgcn_mfma_f32_16x16x32_bf16(b1, a[f][kk], acc[f][1], 0, 0, 0);
      }
    }
    int cbase0 = ct * 2048 + t * 32 + (lane >> 4) * 4;
    #pragma unroll
    for (int f = 0; f < 2; ++f) {
      float vmax = fmaxf(fmaxf(fmaxf(acc[f][0][0], acc[f][0][1]), fmaxf(acc[f][0][2], acc[f][0][3])),
                         fmaxf(fmaxf(acc[f][1][0], acc[f][1][1]), fmaxf(acc[f][1][2], acc[f][1][3])));
      float v = fmaxf(vmax, __shfl_xor(vmax, 16));
      v = fmaxf(v, __shfl_xor(v, 32));
      runmax[f] = fmaxf(runmax[f], v);
      float thr = runmax[f] - MARGIN;
      if (vmax >= thr) {
        unsigned int hm = 0;
        hm |= (acc[f][0][0] >= thr) ? 0x01u : 0u;
        hm |= (acc[f][0][1] >= thr) ? 0x02u : 0u;
        hm |= (acc[f][0][2] >= thr) ? 0x04u : 0u;
        hm |= (acc[f][0][3] >= thr) ? 0x08u : 0u;
        hm |= (acc[f][1][0] >= thr) ? 0x10u : 0u;
        hm |= (acc[f][1][1] >= thr) ? 0x20u : 0u;
        hm |= (acc[f][1][2] >= thr) ? 0x40u : 0u;
        hm |= (acc[f][1][3] >= thr) ? 0x80u : 0u;
        int q = q0w + f * 16 + (lane & 15);
        int pos = atomicAdd(&cnt[q], __popc(hm));
        #pragma unroll
        for (int j = 0; j < 2; ++j)
          #pragma unroll
          for (int r = 0; r < 4; ++r)
            if (hm & (1u << (j * 4 + r))) {
              if (pos < CAP)
                cand[((size_t)q << 7) + pos] =
                    (__float_as_uint(acc[f][j][r]) & 0xFFFFE000u) |
                    (unsigned int)(cbase0 + j * 16 + r);
              ++pos;
            }
      }
    }
    asm volatile("s_waitcnt vmcnt(0)" ::: "memory");
    __builtin_amdgcn_s_barrier();
    cur ^= 1;
  }
  // store exact per-split final max (for exact global threshold in rescore)
  #pragma unroll
  for (int f = 0; f < 2; ++f)
    if (lane < 16) qbest[(size_t)ct * NQ + q0w + f * 16 + lane] = runmax[f];
}

// ---------- exact fp32 rescore: exact global thr, filter stored, rescore ----------
__global__ __launch_bounds__(256) void k_rescore(const float* __restrict__ z,
                                                 const float* __restrict__ emb,
                                                 const float* __restrict__ se,
                                                 const float* __restrict__ s2,
                                                 const int* __restrict__ cnt,
                                                 const unsigned int* __restrict__ cand,
                                                 const float* __restrict__ qbest,
                                                 int* __restrict__ best) {
  int q = blockIdx.x * 4 + (threadIdx.x >> 6);
  int lane = threadIdx.x & 63;
  int b = q >> 10;
  int hw = q & 1023;
  float zr[4];
  #pragma unroll
  for (int j = 0; j < 4; ++j)
    zr[j] = z[(size_t)((b << 8) + lane * 4 + j) * HWsz + hw];
  float s2q = s2[q];
  int n = cnt[q];
  float bd = 3.4028235e38f;
  int bi = 0x7fffffff;
  if (n > 0 && n <= CAP) {
    float M = fmaxf(fmaxf(qbest[q], qbest[NQ + q]),
                    fmaxf(qbest[2 * NQ + q], qbest[3 * NQ + q]));
    float thr = M - MARGIN - 4e-6f;   // packing-truncation guard
    unsigned int p0 = (lane < n) ? cand[((size_t)q << 7) + lane] : 0u;
    unsigned int p1 = (lane + 64 < n) ? cand[((size_t)q << 7) + lane + 64] : 0u;
    bool h0 = (lane < n) && (__uint_as_float(p0 & 0xFFFFE000u) >= thr);
    bool h1 = (lane + 64 < n) && (__uint_as_float(p1 & 0xFFFFE000u) >= thr);
    #pragma unroll
    for (int half = 0; half < 2; ++half) {
      unsigned long long mask = __ballot(half == 0 ? h0 : h1);
      unsigned int pw = half == 0 ? p0 : p1;
      while (mask) {
        int sl = __ffsll(mask) - 1;
        mask &= mask - 1;
        int c = __shfl((int)pw, sl) & 0x1FFF;
        float4 e = *(const float4*)(emb + (size_t)c * DIM + lane * 4);
        float pr = fmaf(zr[0], e.x, fmaf(zr[1], e.y, fmaf(zr[2], e.z, zr[3] * e.w)));
        #pragma unroll
        for (int m = 1; m <= 32; m <<= 1) pr += __shfl_xor(pr, m);
        float tt = s2q + se[c];
        float d = tt - 2.0f * pr;
        if (d < bd || (d == bd && c < bi)) { bd = d; bi = c; }
      }
    }
  } else {
    for (int c = 0; c < NE; ++c) {
      float4 e = *(const float4*)(emb + (size_t)c * DIM + lane * 4);
      float pr = fmaf(zr[0], e.x, fmaf(zr[1], e.y, fmaf(zr[2], e.z, zr[3] * e.w)));
      #pragma unroll
      for (int m = 1; m <= 32; m <<= 1) pr += __shfl_xor(pr, m);
      float tt = s2q + se[c];
      float d = tt - 2.0f * pr;
      if (d < bd || (d == bd && c < bi)) { bd = d; bi = c; }
    }
  }
  if (lane == 0) best[q] = bi;
}

// ---------- output writer: z_q (straight-through) + indices as float ----------
__global__ __launch_bounds__(256) void k_out(const float* __restrict__ z,
                                             const float* __restrict__ emb,
                                             const int* __restrict__ best,
                                             float* __restrict__ out) {
  int i = blockIdx.x * 256 + threadIdx.x;
  if (i < NQ * DIM) {
    int bb = i >> 18;
    int c  = (i >> 10) & 255;
    int hw = i & 1023;
    int n  = (bb << 10) + hw;
    float zv = z[i];
    float evv = emb[(size_t)best[n] * DIM + c];
    out[i] = zv + (evv - zv);
  } else {
    int n = i - NQ * DIM;
    out[i] = (float)best[n];
  }
}

extern "C" void kernel_launch(void* const* d_in, const int* in_sizes, int n_in,
                              void* d_out, int out_size, void* d_ws, size_t ws_size,
                              hipStream_t stream) {
  const float* z   = (const float*)d_in[0];
  const float* emb = (const float*)d_in[1];
  float* out = (float*)d_out;

  char* ws = (char*)d_ws;
  float*        se    = (float*)(ws + 0);                   //  32 KB
  float*        s2    = (float*)(ws + 32768);               // 128 KB
  int*          best  = (int*)  (ws + 163840);              // 128 KB
  int*          cnt   = (int*)  (ws + 294912);              // 128 KB
  float*        qbest = (float*)(ws + 425984);              // 512 KB (4 x NQ f32)
  unsigned int* cand  = (unsigned int*)(ws + 950272);       //  16 MB (NQ x 128 u32)
  unsigned short* za  = (unsigned short*)(ws + 17727488);   //  16 MB
  unsigned short* ebf = (unsigned short*)(ws + 34504704);   //   4 MB  (total ~37 MB)

  k_se     <<<NE / 4, 256, 0, stream>>>(emb, se);
  k_s2     <<<NQ / 64, 256, 0, stream>>>(z, s2);
  k_ebf    <<<1024, 256, 0, stream>>>(emb, ebf);
  k_tr     <<<2048, 256, 0, stream>>>(z, za);
  hipMemsetAsync(cnt, 0, NQ * sizeof(int), stream);
  k_score  <<<1024, 256, 0, stream>>>(za, ebf, cnt, cand, qbest);
  k_rescore<<<NQ / 4, 256, 0, stream>>>(z, emb, se, s2, cnt, cand, qbest, best);
  k_out    <<<(NQ * DIM + NQ) / 256, 256, 0, stream>>>(z, emb, best, out);
}